// Round 2
// baseline (879.714 us; speedup 1.0000x reference)
//
#include <hip/hip_runtime.h>
#include <hip/hip_bf16.h>

#define N_NODES 100000
#define N_EDGES 600000
#define DIM     128
#define N_REL   8
#define N_GRAPH 64
#define N_LAYER 3
#define NR      (N_NODES * N_REL)   // 800000
#define NB1     782                 // ceil(NR / 1024)

typedef __attribute__((ext_vector_type(4))) float float4v;
typedef __attribute__((ext_vector_type(2))) float float2v;
typedef unsigned long long ull;

// XOR-swizzle, 8-B granules, 128-B rows (B fp8 tiles): 16 granules/row
__device__ __forceinline__ int gswz8(int row, int g) {
    return row * 16 + (g ^ (row & 15));
}

// ---------------- fused prep: edge hist + x0 gather + weight prep + gcnt ----------------
#define W8_TOTAL (N_LAYER * 9 * 8192)   // 221184
#define PB_HIST  2344                   // ceil(600000/256)
#define PB_GATH  12500                  // 100000*32/256
#define PB_WPRE  864                    // 221184/256
#define PB_BCNT  1                      // binary-search block (NO atomics)
#define PB_TOTAL (PB_HIST + PB_GATH + PB_WPRE + PB_BCNT)

__global__ __launch_bounds__(256) void k_prep(
    const int* __restrict__ ei, const int* __restrict__ et, int* __restrict__ counts,
    const int* __restrict__ nt, const float* __restrict__ emb, unsigned int* __restrict__ x8,
    const float* __restrict__ relw, const float* __restrict__ rootw,
    unsigned short* __restrict__ W8,
    const int* __restrict__ batch, int* __restrict__ gcnt)
{
    const int b = blockIdx.x, t = threadIdx.x;
    if (b < PB_HIST) {
        int e = b * 256 + t;
        if (e < N_EDGES) {
            int seg = ei[N_EDGES + e] * N_REL + et[e];
            atomicAdd(&counts[seg], 1);
        }
    } else if (b < PB_HIST + PB_GATH) {
        int gid = (b - PB_HIST) * 256 + t;        // < N_NODES*32 exactly
        int n = gid >> 5, up = gid & 31;
        const float* row = emb + (size_t)nt[n] * DIM;
        int p0 = up * 4;
        float f0 = row[((p0 + 0) & 7) * 16 + ((p0 + 0) >> 3)];
        float f1 = row[((p0 + 1) & 7) * 16 + ((p0 + 1) >> 3)];
        float f2 = row[((p0 + 2) & 7) * 16 + ((p0 + 2) >> 3)];
        float f3 = row[((p0 + 3) & 7) * 16 + ((p0 + 3) >> 3)];
        int u = __builtin_amdgcn_cvt_pk_fp8_f32(f0, f1, 0, false);
        u = __builtin_amdgcn_cvt_pk_fp8_f32(f2, f3, u, true);
        x8[gid] = (unsigned int)u;
    } else if (b < PB_HIST + PB_GATH + PB_WPRE) {
        int gid = (b - PB_HIST - PB_GATH) * 256 + t;   // < W8_TOTAL exactly
        int l = gid / (9 * 8192);
        int rem = gid - l * 9 * 8192;
        int r = rem >> 13;                 // plane 0..8
        int idx = rem & 8191;
        int n = idx >> 6, p2 = idx & 63;
        int pos0 = 2 * p2, pos1 = 2 * p2 + 1;
        int k0 = (pos0 & 7) * 16 + (pos0 >> 3);
        int k1 = (pos1 & 7) * 16 + (pos1 >> 3);
        float w0, w1;
        if (r < 8) {
            const float* base = relw + ((size_t)(l * 8 + r) * 128) * 128 + n;
            w0 = base[(size_t)k0 * 128];
            w1 = base[(size_t)k1 * 128];
        } else {
            const float* base = rootw + (size_t)l * 128 * 128 + n;
            w0 = base[(size_t)k0 * 128];
            w1 = base[(size_t)k1 * 128];
        }
        int pk = __builtin_amdgcn_cvt_pk_fp8_f32(w0, w1, 0, false);
        W8[gid] = (unsigned short)(pk & 0xffff);
    } else {
        // gcnt via binary search over sorted batch (plain stores, no atomics)
        int g = t;
        if (g < N_GRAPH) {
            int lo = 0, hi = N_NODES;
            while (lo < hi) { int mid = (lo + hi) >> 1; if (batch[mid] < g) lo = mid + 1; else hi = mid; }
            int start = lo;
            lo = 0; hi = N_NODES;
            while (lo < hi) { int mid = (lo + hi) >> 1; if (batch[mid] < g + 1) lo = mid + 1; else hi = mid; }
            gcnt[g] = lo - start;
        }
    }
}

__global__ __launch_bounds__(256) void k_scan1(const int* __restrict__ cnts,
                                               int* __restrict__ part,
                                               int* __restrict__ bsum) {
    __shared__ int sh[256];
    int t = threadIdx.x;
    int base = blockIdx.x * 1024 + t * 4;
    int v0 = (base + 0 < NR) ? cnts[base + 0] : 0;
    int v1 = (base + 1 < NR) ? cnts[base + 1] : 0;
    int v2 = (base + 2 < NR) ? cnts[base + 2] : 0;
    int v3 = (base + 3 < NR) ? cnts[base + 3] : 0;
    int tot = v0 + v1 + v2 + v3;
    sh[t] = tot;
    __syncthreads();
    for (int off = 1; off < 256; off <<= 1) {
        int x = (t >= off) ? sh[t - off] : 0;
        __syncthreads();
        sh[t] += x;
        __syncthreads();
    }
    int exc = sh[t] - tot;
    if (base + 0 < NR) part[base + 0] = exc;
    if (base + 1 < NR) part[base + 1] = exc + v0;
    if (base + 2 < NR) part[base + 2] = exc + v0 + v1;
    if (base + 3 < NR) part[base + 3] = exc + v0 + v1 + v2;
    if (t == 255) bsum[blockIdx.x] = sh[t];
}

__global__ __launch_bounds__(1024) void k_scan2(int* __restrict__ bsum, int nb) {
    __shared__ int sh[1024];
    int t = threadIdx.x;
    int v = (t < nb) ? bsum[t] : 0;
    sh[t] = v;
    __syncthreads();
    for (int off = 1; off < 1024; off <<= 1) {
        int x = (t >= off) ? sh[t - off] : 0;
        __syncthreads();
        sh[t] += x;
        __syncthreads();
    }
    if (t < nb) bsum[t] = sh[t] - v;   // exclusive block offsets
}

__global__ void k_scan3(const int* __restrict__ part, const int* __restrict__ bsum,
                        int* __restrict__ rowptr, int* __restrict__ cursor) {
    int i = blockIdx.x * 256 + threadIdx.x;
    if (i < NR) {
        int v = part[i] + bsum[i >> 10];
        rowptr[i] = v;
        cursor[i] = v;
    }
    if (i == 0) rowptr[NR] = N_EDGES;
}

__global__ void k_scatter(const int* __restrict__ ei, const int* __restrict__ et,
                          int* __restrict__ cursor, int* __restrict__ srcs) {
    int e = blockIdx.x * 256 + threadIdx.x;
    if (e < N_EDGES) {
        int seg = ei[N_EDGES + e] * N_REL + et[e];
        int p = atomicAdd(&cursor[seg], 1);
        srcs[p] = ei[e];
    }
}

// ---------------- FUSED aggregation + dense MFMA GEMM, 3-deep pipeline ----------------
// Round-1 fusion removed the 102-MB Ag8 round-trip but serialized the dependent
// chain (srcs -> gather -> consume) inside each chunk AFTER the MFMA: 92 us at
// 12% MfmaUtil / 7% HBM = pure latency. Fix: pipeline each link one chunk ahead:
//   iter c: issue rowptr(c+3) | issue srcs(c+2) | issue gathers(c+1)
//           | B prefetch(c+1) | MFMA(c) | consume+pack+write Als(c+1) | barrier
// Every load now has >= 1 full MFMA block (~1200 SIMD-cyc) of latency cover.
// srcs prefetch widened to 4/segment (P(cnt>4)=0.13%, Poisson 0.75) so the tail
// almost never runs a dependent srcs->gather chain. Accumulation order per
// segment is unchanged (k ascending) -> bit-identical numerics.
#define BM2 128
__global__ __launch_bounds__(256, 3) void k_gemm(
    const unsigned int* __restrict__ x8in,  // [N][32] fp8 rows (pi order)
    unsigned int* __restrict__ x8out,       // [N][32] fp8 rows
    const unsigned short* __restrict__ W8,  // [9][128n][64kp] fp8 pairs (this layer)
    const float* __restrict__ bias,         // [128]
    const int* __restrict__ rowptr,         // [NR+1], seg = dst*8 + rel
    const int* __restrict__ srcs)           // [E] sorted by seg
{
    __shared__ __align__(16) ull Bls[4096];  // 2 x 16 KB ping-pong (B)
    __shared__ __align__(16) ull Als[2048];  // 4 waves x 4 KB private A chunk
    const int t = threadIdx.x;
    const int wv = t >> 6, lane = t & 63;
    const int quad = lane >> 4, l15 = lane & 15;
    const int oct = lane >> 3, h = lane & 7;
    const int m0 = blockIdx.x * BM2;
    const int gn = m0 + wv * 32 + (lane >> 1);   // node owned by this lane-pair
    const int f = lane & 1;

    float4v acc[2][8];
#pragma unroll
    for (int nt = 0; nt < 8; ++nt) {
        float bc = bias[nt * 16 + l15];
        acc[0][nt] = (float4v){bc, bc, bc, bc};
        acc[1][nt] = (float4v){bc, bc, bc, bc};
    }

    const ull* Xr = (const ull*)x8in;
    const uint4* x4p = (const uint4*)x8in;
    ull* AlsW = Als + wv * 512;              // this wave's region (512 ull)
    uint4* Als4 = (uint4*)AlsW;

    ull bR[8], aR[8];
    uint4 u0[4], u1[4];
    int cc[4], eb[4], s2v[4], s3v[4];

#define ACCUM(U) do {                                                  \
        A0 += __builtin_amdgcn_cvt_pk_f32_fp8((int)(U).x, false);      \
        A1 += __builtin_amdgcn_cvt_pk_f32_fp8((int)(U).x, true);       \
        A2 += __builtin_amdgcn_cvt_pk_f32_fp8((int)(U).y, false);      \
        A3 += __builtin_amdgcn_cvt_pk_f32_fp8((int)(U).y, true);       \
        A4 += __builtin_amdgcn_cvt_pk_f32_fp8((int)(U).z, false);      \
        A5 += __builtin_amdgcn_cvt_pk_f32_fp8((int)(U).z, true);       \
        A6 += __builtin_amdgcn_cvt_pk_f32_fp8((int)(U).w, false);      \
        A7 += __builtin_amdgcn_cvt_pk_f32_fp8((int)(U).w, true);       \
    } while (0)

    // S1: rowptr pair-load for chunk rr (lane 2p -> start, 2p+1 -> end)
    auto rp_load = [&](int rr) -> int {
        int idxp = (gn < N_NODES) ? gn * 8 + rr + f : NR;   // clamp -> cnt 0
        return rowptr[idxp];
    };
    // S2: first-4 srcs of each segment, all-lane parallel (2 loads/lane)
    auto src_load = [&](int val, int& s0, int& s2) {
        int e0l = __shfl(val, lane & 62);
        int cl  = __shfl(val, lane | 1) - e0l;
        s0 = (f < cl) ? srcs[e0l + f] : 0;
        s2 = (f + 2 < cl) ? srcs[e0l + 2 + f] : 0;
    };
    // S3: shuffle per-octet metadata, issue first-2 gathers (held across MFMA)
    auto gat_issue = [&](int val, int sl0, int sl2) {
#pragma unroll
        for (int nn = 0; nn < 4; ++nn) {
            int lw = nn * 8 + oct;
            int e0 = __shfl(val, lw * 2);
            int e1 = __shfl(val, lw * 2 + 1);
            cc[nn] = e1 - e0; eb[nn] = e0;
            int s0 = __shfl(sl0, lw * 2);
            int s1 = __shfl(sl0, lw * 2 + 1);
            s2v[nn] = __shfl(sl2, lw * 2);
            s3v[nn] = __shfl(sl2, lw * 2 + 1);
            if (cc[nn] > 0) u0[nn] = x4p[(size_t)s0 * 8 + h];
            if (cc[nn] > 1) u1[nn] = x4p[(size_t)s1 * 8 + h];
        }
    };
    // S4: issue rare k=2,3 gathers, accumulate (k ascending), pack, write Als
    auto agg_consume = [&]() {
        uint4 u2[4], u3[4];
#pragma unroll
        for (int nn = 0; nn < 4; ++nn) {
            if (cc[nn] > 2) u2[nn] = x4p[(size_t)s2v[nn] * 8 + h];
            if (cc[nn] > 3) u3[nn] = x4p[(size_t)s3v[nn] * 8 + h];
        }
#pragma unroll
        for (int nn = 0; nn < 4; ++nn) {
            int lw = nn * 8 + oct;
            float2v A0 = {0.f, 0.f}, A1 = {0.f, 0.f}, A2 = {0.f, 0.f}, A3 = {0.f, 0.f};
            float2v A4 = {0.f, 0.f}, A5 = {0.f, 0.f}, A6 = {0.f, 0.f}, A7 = {0.f, 0.f};
            if (cc[nn] > 0) ACCUM(u0[nn]);
            if (cc[nn] > 1) ACCUM(u1[nn]);
            if (cc[nn] > 2) ACCUM(u2[nn]);
            if (cc[nn] > 3) ACCUM(u3[nn]);
#pragma unroll 1
            for (int k = 4; k < cc[nn]; ++k) {    // ultra-rare (P ~ 0.13%/seg)
                int s = srcs[eb[nn] + k];
                uint4 uu = x4p[(size_t)s * 8 + h];
                ACCUM(uu);
            }
            float inv = (cc[nn] > 0) ? 1.0f / (float)cc[nn] : 0.f;
            float2v iv = {inv, inv};
            A0 *= iv; A1 *= iv; A2 *= iv; A3 *= iv;
            A4 *= iv; A5 *= iv; A6 *= iv; A7 *= iv;
            int w0 = __builtin_amdgcn_cvt_pk_fp8_f32(A0.x, A0.y, 0, false);
            w0 = __builtin_amdgcn_cvt_pk_fp8_f32(A1.x, A1.y, w0, true);
            int w1 = __builtin_amdgcn_cvt_pk_fp8_f32(A2.x, A2.y, 0, false);
            w1 = __builtin_amdgcn_cvt_pk_fp8_f32(A3.x, A3.y, w1, true);
            int w2 = __builtin_amdgcn_cvt_pk_fp8_f32(A4.x, A4.y, 0, false);
            w2 = __builtin_amdgcn_cvt_pk_fp8_f32(A5.x, A5.y, w2, true);
            int w3 = __builtin_amdgcn_cvt_pk_fp8_f32(A6.x, A6.y, 0, false);
            w3 = __builtin_amdgcn_cvt_pk_fp8_f32(A7.x, A7.y, w3, true);
            uint4 w; w.x = (unsigned int)w0; w.y = (unsigned int)w1;
            w.z = (unsigned int)w2; w.w = (unsigned int)w3;
            Als4[(lw >> 4) * 128 + h * 16 + ((lw & 15) ^ h)] = w;
        }
    };

    // ---- prologue: B(0) + chunk 0 fully staged + rowptr/srcs pipeline primed ----
    {
        const ull* Wc = (const ull*)W8;
#pragma unroll
        for (int i = 0; i < 8; ++i) bR[i] = Wc[t + 256 * i];
    }
    int vS3 = rp_load(0);            // val chunk 0 (consumed now)
    int vS2 = rp_load(1);            // val chunk 1
    int vNew = rp_load(2);           // val chunk 2
    int sl0A, sl2A, sl0N, sl2N;
    src_load(vS3, sl0A, sl2A);       // srcs chunk 0
    gat_issue(vS3, sl0A, sl2A);      // gathers chunk 0
    src_load(vS2, sl0A, sl2A);       // srcs chunk 1 (held for loop iter 0)
    agg_consume();                   // Als chunk 0
    vS3 = vS2; vS2 = vNew;
#pragma unroll
    for (int i = 0; i < 8; ++i) {
        int idx = t + 256 * i;
        Bls[gswz8(idx >> 4, idx & 15)] = bR[i];
    }
    __syncthreads();

    // steady state entering iter c: vS3=val[c+1], vS2=val[c+2],
    // (sl0A,sl2A)=srcs[c+1]; Als holds chunk c; Bls[cur] holds chunk c.
    for (int c = 0; c < 9; ++c) {
        const int cur = (c & 1) * 2048;
        if (c <= 4) vNew = rp_load(c + 3);               // rowptr chunk c+3
        if (c <= 5) src_load(vS2, sl0N, sl2N);           // srcs chunk c+2
        if (c <= 6) gat_issue(vS3, sl0A, sl2A);          // gathers chunk c+1
        if (c < 8) {                                     // B prefetch chunk c+1
            const ull* Wc = (const ull*)(W8 + (size_t)(c + 1) * 8192);
#pragma unroll
            for (int i = 0; i < 8; ++i) bR[i] = Wc[t + 256 * i];
        }
        if (c == 7) {                                    // root A from x8 rows
#pragma unroll
            for (int i = 0; i < 8; ++i) {
                int rt = i >> 2, kk = i & 3;
                aR[i] = Xr[(size_t)(m0 + wv * 32 + rt * 16 + l15) * 16 + kk * 4 + quad];
            }
        }
#pragma unroll
        for (int kk = 0; kk < 4; ++kk) {
            long long a0, a1;
            if (c == 8) {
                a0 = (long long)aR[kk];
                a1 = (long long)aR[4 + kk];
            } else {
                int j4 = kk * 4 + quad;        // byte-pair group 0..15
                int h2 = j4 >> 1, hf = j4 & 1;
                int slot = ((h2 * 16 + (l15 ^ h2)) << 1) | hf;
                a0 = (long long)AlsW[slot];
                a1 = (long long)AlsW[256 + slot];
            }
            int g = kk * 4 + quad;
#pragma unroll
            for (int nt = 0; nt < 8; ++nt) {
                long long b8 = (long long)Bls[cur + (nt * 16 + l15) * 16 + (g ^ l15)];
                acc[0][nt] = __builtin_amdgcn_mfma_f32_16x16x32_fp8_fp8(a0, b8, acc[0][nt], 0, 0, 0);
                acc[1][nt] = __builtin_amdgcn_mfma_f32_16x16x32_fp8_fp8(a1, b8, acc[1][nt], 0, 0, 0);
            }
        }
        if (c <= 6) agg_consume();             // Als chunk c+1 (wave-private: no barrier)
        if (c < 8) {
            const int nxt = ((c + 1) & 1) * 2048;
#pragma unroll
            for (int i = 0; i < 8; ++i) {
                int idx = t + 256 * i;
                Bls[nxt + gswz8(idx >> 4, idx & 15)] = bR[i];
            }
            __syncthreads();
        }
        vS3 = vS2; vS2 = vNew; sl0A = sl0N; sl2A = sl2N;
    }
#undef ACCUM

    // ---- epilogue: relu, fp8 pack (pi order rows) ----
    ull* outs = (ull*)x8out;
#pragma unroll
    for (int rt = 0; rt < 2; ++rt) {
#pragma unroll
        for (int i = 0; i < 4; ++i) {
            int row = m0 + wv * 32 + rt * 16 + quad * 4 + i;
            float v0 = acc[rt][0][i], v1 = acc[rt][1][i];
            float v2 = acc[rt][2][i], v3 = acc[rt][3][i];
            float v4 = acc[rt][4][i], v5 = acc[rt][5][i];
            float v6 = acc[rt][6][i], v7 = acc[rt][7][i];
            v0 = v0 > 0.f ? v0 : 0.f;  v1 = v1 > 0.f ? v1 : 0.f;
            v2 = v2 > 0.f ? v2 : 0.f;  v3 = v3 > 0.f ? v3 : 0.f;
            v4 = v4 > 0.f ? v4 : 0.f;  v5 = v5 > 0.f ? v5 : 0.f;
            v6 = v6 > 0.f ? v6 : 0.f;  v7 = v7 > 0.f ? v7 : 0.f;
            int lo = __builtin_amdgcn_cvt_pk_fp8_f32(v0, v1, 0, false);
            lo = __builtin_amdgcn_cvt_pk_fp8_f32(v2, v3, lo, true);
            int hi = __builtin_amdgcn_cvt_pk_fp8_f32(v4, v5, 0, false);
            hi = __builtin_amdgcn_cvt_pk_fp8_f32(v6, v7, hi, true);
            if (row < N_NODES) {
                ull w = ((ull)(unsigned int)hi << 32) | (unsigned int)lo;
                outs[(size_t)row * 16 + l15] = w;
            }
        }
    }
}

// ---------------- global mean pool (batch sorted): 64 nodes/wave, fp8 in ----------------
__global__ __launch_bounds__(256) void k_pool(const unsigned int* __restrict__ x8,
                                              const int* __restrict__ batch,
                                              float* __restrict__ gsum) {
    const int wv = threadIdx.x >> 6, lane = threadIdx.x & 63;
    const int n0 = (blockIdx.x * 4 + wv) * 64;
    if (n0 >= N_NODES) return;
    int n1 = n0 + 64;
    if (n1 > N_NODES) n1 = N_NODES;
    const int nb = n1 - n0;
    const unsigned short* xs = (const unsigned short*)x8;   // row = 64 ushorts
    int bb = batch[n0 + (lane < nb ? lane : nb - 1)];
    float2v A = {0.f, 0.f};
    int cur = __shfl(bb, 0);
    for (int base = 0; base < nb; base += 8) {
        unsigned int u[8];
        int m = nb - base;
#pragma unroll
        for (int qq = 0; qq < 8; ++qq)
            if (qq < m) u[qq] = xs[(size_t)(n0 + base + qq) * 64 + lane];
#pragma unroll
        for (int qq = 0; qq < 8; ++qq) {
            if (qq < m) {
                int b = __shfl(bb, base + qq);
                if (b != cur) {
                    atomicAdd(&gsum[cur * 128 + lane * 2], A.x);
                    atomicAdd(&gsum[cur * 128 + lane * 2 + 1], A.y);
                    A = (float2v){0.f, 0.f};
                    cur = b;
                }
                A += __builtin_amdgcn_cvt_pk_f32_fp8((int)u[qq], false);
            }
        }
    }
    atomicAdd(&gsum[cur * 128 + lane * 2], A.x);
    atomicAdd(&gsum[cur * 128 + lane * 2 + 1], A.y);
}

// ---------------- MLP heads (fp32; un-permutes g from pi byte-position order) ----------
__global__ __launch_bounds__(128) void k_heads(
    const float* __restrict__ gsum, const int* __restrict__ gcnt,
    const float* __restrict__ rw1, const float* __restrict__ rb1,
    const float* __restrict__ rw2, const float* __restrict__ rb2,
    const float* __restrict__ sw1, const float* __restrict__ sb1,
    const float* __restrict__ sw2, const float* __restrict__ sb2,
    float* __restrict__ out) {
    __shared__ float g[128];
    __shared__ float parts[2];
    int b = blockIdx.x, t = threadIdx.x;
    int c = gcnt[b];
    float invc = 1.0f / (float)(c > 0 ? c : 1);
    g[((t & 7) << 4) | (t >> 3)] = gsum[b * 128 + t] * invc;   // position -> natural col
    __syncthreads();
    float acc = rb1[t];
    for (int d = 0; d < 128; ++d) acc += g[d] * rw1[d * 128 + t];
    float h = acc > 0.f ? acc : 0.f;
    float p = h * rw2[t];
    for (int o = 32; o > 0; o >>= 1) p += __shfl_down(p, o);
    if ((t & 63) == 0) parts[t >> 6] = p;
    __syncthreads();
    if (t == 0) out[b] = parts[0] + parts[1] + rb2[0];
    __syncthreads();
    acc = sb1[t];
    for (int d = 0; d < 128; ++d) acc += g[d] * sw1[d * 128 + t];
    h = acc > 0.f ? acc : 0.f;
    p = h * sw2[t];
    for (int o = 32; o > 0; o >>= 1) p += __shfl_down(p, o);
    if ((t & 63) == 0) parts[t >> 6] = p;
    __syncthreads();
    if (t == 0) out[64 + b] = parts[0] + parts[1] + sb2[0];
}

extern "C" void kernel_launch(void* const* d_in, const int* in_sizes, int n_in,
                              void* d_out, int out_size, void* d_ws, size_t ws_size,
                              hipStream_t stream) {
    const int*   node_type  = (const int*)d_in[0];
    const int*   edge_index = (const int*)d_in[1];
    const int*   edge_type  = (const int*)d_in[2];
    const int*   batch      = (const int*)d_in[3];
    const float* node_emb   = (const float*)d_in[4];
    const float* rel_w      = (const float*)d_in[5];
    const float* root_w     = (const float*)d_in[6];
    const float* bias       = (const float*)d_in[7];
    const float* rw1        = (const float*)d_in[8];
    const float* rb1        = (const float*)d_in[9];
    const float* rw2        = (const float*)d_in[10];
    const float* rb2        = (const float*)d_in[11];
    const float* sw1        = (const float*)d_in[12];
    const float* sb1        = (const float*)d_in[13];
    const float* sw2        = (const float*)d_in[14];
    const float* sb2        = (const float*)d_in[15];
    float* out = (float*)d_out;

    char* ws = (char*)d_ws;
    size_t off = 0;
    auto alloc = [&](size_t bytes) -> void* {
        void* p = ws + off;
        off += (bytes + 255) & ~(size_t)255;
        return p;
    };
    // ---- persistent region ----
    unsigned int*   x8a    = (unsigned int*)alloc((size_t)N_NODES * 32 * 4);  // 12.8 MB
    unsigned int*   x8b    = (unsigned int*)alloc((size_t)N_NODES * 32 * 4);
    int*            rowptr = (int*)alloc((size_t)(NR + 1) * 4);
    int*            srcs   = (int*)alloc((size_t)N_EDGES * 4);
    int*            bsum   = (int*)alloc(1024 * 4);
    unsigned short* W8     = (unsigned short*)alloc((size_t)W8_TOTAL * 2);
    float*          gsum   = (float*)alloc((64 * 128 + 64) * 4);
    int*            gcnt   = (int*)(gsum + 64 * 128);
    // ---- scratch region: sort temps ----
    int*            cursor = (int*)alloc((size_t)NR * 4);
    int*            counts = (int*)alloc((size_t)NR * 4);
    if (off > ws_size) return;                     // cannot run at all

    // zero scratch via memset nodes (graph-capturable), then fused prep + edge sort
    hipMemsetAsync(counts, 0, (size_t)NR * 4, stream);
    hipMemsetAsync(gsum, 0, (size_t)(64 * 128 + 64) * 4, stream);
    k_prep<<<PB_TOTAL, 256, 0, stream>>>(edge_index, edge_type, counts,
                                         node_type, node_emb, x8a,
                                         rel_w, root_w, W8, batch, gcnt);
    k_scan1<<<NB1, 256, 0, stream>>>(counts, cursor, bsum);
    k_scan2<<<1, 1024, 0, stream>>>(bsum, NB1);
    k_scan3<<<(NR + 255) / 256, 256, 0, stream>>>(cursor, bsum, rowptr, cursor);
    k_scatter<<<(N_EDGES + 255) / 256, 256, 0, stream>>>(edge_index, edge_type, cursor, srcs);

    unsigned int* xcur = x8a;
    unsigned int* xnext = x8b;
    const int gb = (N_NODES + BM2 - 1) / BM2;      // 782
    for (int l = 0; l < N_LAYER; ++l) {
        const unsigned short* W8l = W8 + (size_t)l * 9 * 8192;
        const float* bl = bias + (size_t)l * 128;
        k_gemm<<<gb, 256, 0, stream>>>(xcur, xnext, W8l, bl, rowptr, srcs);
        unsigned int* tmp = xcur; xcur = xnext; xnext = tmp;
    }

    // pool + heads (final activations are in xcur after swap)
    k_pool<<<(N_NODES + 255) / 256, 256, 0, stream>>>(xcur, batch, gsum);
    k_heads<<<64, 128, 0, stream>>>(gsum, gcnt, rw1, rb1, rw2, rb2,
                                    sw1, sb1, sw2, sb2, out);
}

// Round 3
// 388.315 us; speedup vs baseline: 2.2655x; 2.2655x over previous
//
#include <hip/hip_runtime.h>
#include <hip/hip_bf16.h>

#define N_NODES 100000
#define N_EDGES 600000
#define DIM     128
#define N_REL   8
#define N_GRAPH 64
#define N_LAYER 3
#define NR      (N_NODES * N_REL)   // 800000
#define NB1     782                 // ceil(NR / 1024)

typedef __attribute__((ext_vector_type(4))) float float4v;
typedef __attribute__((ext_vector_type(2))) float float2v;
typedef unsigned long long ull;

// XOR-swizzle, 8-B granules, 128-B rows (B fp8 tiles): 16 granules/row
__device__ __forceinline__ int gswz8(int row, int g) {
    return row * 16 + (g ^ (row & 15));
}

// ---------------- fused prep: edge hist + x0 gather + weight prep + gcnt ----------------
#define W8_TOTAL (N_LAYER * 9 * 8192)   // 221184
#define PB_HIST  2344                   // ceil(600000/256)
#define PB_GATH  12500                  // 100000*32/256
#define PB_WPRE  864                    // 221184/256
#define PB_BCNT  1                      // binary-search block (NO atomics)
#define PB_TOTAL (PB_HIST + PB_GATH + PB_WPRE + PB_BCNT)

__global__ __launch_bounds__(256) void k_prep(
    const int* __restrict__ ei, const int* __restrict__ et, int* __restrict__ counts,
    const int* __restrict__ nt, const float* __restrict__ emb, unsigned int* __restrict__ x8,
    const float* __restrict__ relw, const float* __restrict__ rootw,
    unsigned short* __restrict__ W8,
    const int* __restrict__ batch, int* __restrict__ gcnt)
{
    const int b = blockIdx.x, t = threadIdx.x;
    if (b < PB_HIST) {
        int e = b * 256 + t;
        if (e < N_EDGES) {
            int seg = ei[N_EDGES + e] * N_REL + et[e];
            atomicAdd(&counts[seg], 1);
        }
    } else if (b < PB_HIST + PB_GATH) {
        int gid = (b - PB_HIST) * 256 + t;        // < N_NODES*32 exactly
        int n = gid >> 5, up = gid & 31;
        const float* row = emb + (size_t)nt[n] * DIM;
        int p0 = up * 4;
        float f0 = row[((p0 + 0) & 7) * 16 + ((p0 + 0) >> 3)];
        float f1 = row[((p0 + 1) & 7) * 16 + ((p0 + 1) >> 3)];
        float f2 = row[((p0 + 2) & 7) * 16 + ((p0 + 2) >> 3)];
        float f3 = row[((p0 + 3) & 7) * 16 + ((p0 + 3) >> 3)];
        int u = __builtin_amdgcn_cvt_pk_fp8_f32(f0, f1, 0, false);
        u = __builtin_amdgcn_cvt_pk_fp8_f32(f2, f3, u, true);
        x8[gid] = (unsigned int)u;
    } else if (b < PB_HIST + PB_GATH + PB_WPRE) {
        int gid = (b - PB_HIST - PB_GATH) * 256 + t;   // < W8_TOTAL exactly
        int l = gid / (9 * 8192);
        int rem = gid - l * 9 * 8192;
        int r = rem >> 13;                 // plane 0..8
        int idx = rem & 8191;
        int n = idx >> 6, p2 = idx & 63;
        int pos0 = 2 * p2, pos1 = 2 * p2 + 1;
        int k0 = (pos0 & 7) * 16 + (pos0 >> 3);
        int k1 = (pos1 & 7) * 16 + (pos1 >> 3);
        float w0, w1;
        if (r < 8) {
            const float* base = relw + ((size_t)(l * 8 + r) * 128) * 128 + n;
            w0 = base[(size_t)k0 * 128];
            w1 = base[(size_t)k1 * 128];
        } else {
            const float* base = rootw + (size_t)l * 128 * 128 + n;
            w0 = base[(size_t)k0 * 128];
            w1 = base[(size_t)k1 * 128];
        }
        int pk = __builtin_amdgcn_cvt_pk_fp8_f32(w0, w1, 0, false);
        W8[gid] = (unsigned short)(pk & 0xffff);
    } else {
        // gcnt via binary search over sorted batch (plain stores, no atomics)
        int g = t;
        if (g < N_GRAPH) {
            int lo = 0, hi = N_NODES;
            while (lo < hi) { int mid = (lo + hi) >> 1; if (batch[mid] < g) lo = mid + 1; else hi = mid; }
            int start = lo;
            lo = 0; hi = N_NODES;
            while (lo < hi) { int mid = (lo + hi) >> 1; if (batch[mid] < g + 1) lo = mid + 1; else hi = mid; }
            gcnt[g] = lo - start;
        }
    }
}

__global__ __launch_bounds__(256) void k_scan1(const int* __restrict__ cnts,
                                               int* __restrict__ part,
                                               int* __restrict__ bsum) {
    __shared__ int sh[256];
    int t = threadIdx.x;
    int base = blockIdx.x * 1024 + t * 4;
    int v0 = (base + 0 < NR) ? cnts[base + 0] : 0;
    int v1 = (base + 1 < NR) ? cnts[base + 1] : 0;
    int v2 = (base + 2 < NR) ? cnts[base + 2] : 0;
    int v3 = (base + 3 < NR) ? cnts[base + 3] : 0;
    int tot = v0 + v1 + v2 + v3;
    sh[t] = tot;
    __syncthreads();
    for (int off = 1; off < 256; off <<= 1) {
        int x = (t >= off) ? sh[t - off] : 0;
        __syncthreads();
        sh[t] += x;
        __syncthreads();
    }
    int exc = sh[t] - tot;
    if (base + 0 < NR) part[base + 0] = exc;
    if (base + 1 < NR) part[base + 1] = exc + v0;
    if (base + 2 < NR) part[base + 2] = exc + v0 + v1;
    if (base + 3 < NR) part[base + 3] = exc + v0 + v1 + v2;
    if (t == 255) bsum[blockIdx.x] = sh[t];
}

__global__ __launch_bounds__(1024) void k_scan2(int* __restrict__ bsum, int nb) {
    __shared__ int sh[1024];
    int t = threadIdx.x;
    int v = (t < nb) ? bsum[t] : 0;
    sh[t] = v;
    __syncthreads();
    for (int off = 1; off < 1024; off <<= 1) {
        int x = (t >= off) ? sh[t - off] : 0;
        __syncthreads();
        sh[t] += x;
        __syncthreads();
    }
    if (t < nb) bsum[t] = sh[t] - v;   // exclusive block offsets
}

__global__ void k_scan3(const int* __restrict__ part, const int* __restrict__ bsum,
                        int* __restrict__ rowptr, int* __restrict__ cursor) {
    int i = blockIdx.x * 256 + threadIdx.x;
    if (i < NR) {
        int v = part[i] + bsum[i >> 10];
        rowptr[i] = v;
        cursor[i] = v;
    }
    if (i == 0) rowptr[NR] = N_EDGES;
}

__global__ void k_scatter(const int* __restrict__ ei, const int* __restrict__ et,
                          int* __restrict__ cursor, int* __restrict__ srcs) {
    int e = blockIdx.x * 256 + threadIdx.x;
    if (e < N_EDGES) {
        int seg = ei[N_EDGES + e] * N_REL + et[e];
        int p = atomicAdd(&cursor[seg], 1);
        srcs[p] = ei[e];
    }
}

// ---------------- FUSED aggregation + dense MFMA GEMM, 3-deep pipeline ----------------
// Round-2 post-mortem: the pipeline state (u0..u3, cc/eb/s2v/s3v, rotating vals)
// lived in a NON-unrolled loop with runtime guards -> compiler allocated it in
// scratch (VGPR 84, WRITE_SIZE 315 MB of spill traffic, 236 us). Rule #20 fix:
// FULLY UNROLL the 9-chunk loop so every guard is compile-time and every array
// index static -> state becomes SSA in registers. launch_bounds(256,2) (not ,3)
// so the allocator targets <=256 VGPR instead of spilling to reach 170.
// Schedule per iter c (unchanged from r2, now all compile-time):
//   rowptr(c+3) | srcs(c+2) | gathers(c+1) | B prefetch(c+1) | MFMA(c)
//   | consume+pack+write Als(c+1) | B store | barrier
#define BM2 128
__global__ __launch_bounds__(256, 2) void k_gemm(
    const unsigned int* __restrict__ x8in,  // [N][32] fp8 rows (pi order)
    unsigned int* __restrict__ x8out,       // [N][32] fp8 rows
    const unsigned short* __restrict__ W8,  // [9][128n][64kp] fp8 pairs (this layer)
    const float* __restrict__ bias,         // [128]
    const int* __restrict__ rowptr,         // [NR+1], seg = dst*8 + rel
    const int* __restrict__ srcs)           // [E] sorted by seg
{
    __shared__ __align__(16) ull Bls[4096];  // 2 x 16 KB ping-pong (B)
    __shared__ __align__(16) ull Als[2048];  // 4 waves x 4 KB private A chunk
    const int t = threadIdx.x;
    const int wv = t >> 6, lane = t & 63;
    const int quad = lane >> 4, l15 = lane & 15;
    const int oct = lane >> 3, h = lane & 7;
    const int m0 = blockIdx.x * BM2;
    const int gn = m0 + wv * 32 + (lane >> 1);   // node owned by this lane-pair
    const int f = lane & 1;

    float4v acc[2][8];
#pragma unroll
    for (int nt = 0; nt < 8; ++nt) {
        float bc = bias[nt * 16 + l15];
        acc[0][nt] = (float4v){bc, bc, bc, bc};
        acc[1][nt] = (float4v){bc, bc, bc, bc};
    }

    const ull* Xr = (const ull*)x8in;
    const uint4* x4p = (const uint4*)x8in;
    ull* AlsW = Als + wv * 512;              // this wave's region (512 ull)
    uint4* Als4 = (uint4*)AlsW;

    ull bR[8], aR[8];
    uint4 u0[4], u1[4];
    int cc[4], eb[4], s2v[4], s3v[4];

#define ACCUM(U) do {                                                  \
        A0 += __builtin_amdgcn_cvt_pk_f32_fp8((int)(U).x, false);      \
        A1 += __builtin_amdgcn_cvt_pk_f32_fp8((int)(U).x, true);       \
        A2 += __builtin_amdgcn_cvt_pk_f32_fp8((int)(U).y, false);      \
        A3 += __builtin_amdgcn_cvt_pk_f32_fp8((int)(U).y, true);       \
        A4 += __builtin_amdgcn_cvt_pk_f32_fp8((int)(U).z, false);      \
        A5 += __builtin_amdgcn_cvt_pk_f32_fp8((int)(U).z, true);       \
        A6 += __builtin_amdgcn_cvt_pk_f32_fp8((int)(U).w, false);      \
        A7 += __builtin_amdgcn_cvt_pk_f32_fp8((int)(U).w, true);       \
    } while (0)

    // S1: rowptr pair-load for chunk rr (lane 2p -> start, 2p+1 -> end)
    auto rp_load = [&](int rr) -> int {
        int idxp = (gn < N_NODES) ? gn * 8 + rr + f : NR;   // clamp -> cnt 0
        return rowptr[idxp];
    };
    // S2: first-4 srcs of each segment, all-lane parallel (2 loads/lane)
    auto src_load = [&](int val, int& s0, int& s2) {
        int e0l = __shfl(val, lane & 62);
        int cl  = __shfl(val, lane | 1) - e0l;
        s0 = (f < cl) ? srcs[e0l + f] : 0;
        s2 = (f + 2 < cl) ? srcs[e0l + 2 + f] : 0;
    };
    // S3: shuffle per-octet metadata, issue first-2 gathers (held across MFMA)
    auto gat_issue = [&](int val, int sl0, int sl2) {
#pragma unroll
        for (int nn = 0; nn < 4; ++nn) {
            int lw = nn * 8 + oct;
            int e0 = __shfl(val, lw * 2);
            int e1 = __shfl(val, lw * 2 + 1);
            cc[nn] = e1 - e0; eb[nn] = e0;
            int s0 = __shfl(sl0, lw * 2);
            int s1 = __shfl(sl0, lw * 2 + 1);
            s2v[nn] = __shfl(sl2, lw * 2);
            s3v[nn] = __shfl(sl2, lw * 2 + 1);
            if (cc[nn] > 0) u0[nn] = x4p[(size_t)s0 * 8 + h];
            if (cc[nn] > 1) u1[nn] = x4p[(size_t)s1 * 8 + h];
        }
    };
    // S4: issue rare k=2,3 gathers, accumulate (k ascending), pack, write Als
    auto agg_consume = [&]() {
        uint4 u2[4], u3[4];
#pragma unroll
        for (int nn = 0; nn < 4; ++nn) {
            if (cc[nn] > 2) u2[nn] = x4p[(size_t)s2v[nn] * 8 + h];
            if (cc[nn] > 3) u3[nn] = x4p[(size_t)s3v[nn] * 8 + h];
        }
#pragma unroll
        for (int nn = 0; nn < 4; ++nn) {
            int lw = nn * 8 + oct;
            float2v A0 = {0.f, 0.f}, A1 = {0.f, 0.f}, A2 = {0.f, 0.f}, A3 = {0.f, 0.f};
            float2v A4 = {0.f, 0.f}, A5 = {0.f, 0.f}, A6 = {0.f, 0.f}, A7 = {0.f, 0.f};
            if (cc[nn] > 0) ACCUM(u0[nn]);
            if (cc[nn] > 1) ACCUM(u1[nn]);
            if (cc[nn] > 2) ACCUM(u2[nn]);
            if (cc[nn] > 3) ACCUM(u3[nn]);
#pragma unroll 1
            for (int k = 4; k < cc[nn]; ++k) {    // ultra-rare (P ~ 0.13%/seg)
                int s = srcs[eb[nn] + k];
                uint4 uu = x4p[(size_t)s * 8 + h];
                ACCUM(uu);
            }
            float inv = (cc[nn] > 0) ? 1.0f / (float)cc[nn] : 0.f;
            float2v iv = {inv, inv};
            A0 *= iv; A1 *= iv; A2 *= iv; A3 *= iv;
            A4 *= iv; A5 *= iv; A6 *= iv; A7 *= iv;
            int w0 = __builtin_amdgcn_cvt_pk_fp8_f32(A0.x, A0.y, 0, false);
            w0 = __builtin_amdgcn_cvt_pk_fp8_f32(A1.x, A1.y, w0, true);
            int w1 = __builtin_amdgcn_cvt_pk_fp8_f32(A2.x, A2.y, 0, false);
            w1 = __builtin_amdgcn_cvt_pk_fp8_f32(A3.x, A3.y, w1, true);
            int w2 = __builtin_amdgcn_cvt_pk_fp8_f32(A4.x, A4.y, 0, false);
            w2 = __builtin_amdgcn_cvt_pk_fp8_f32(A5.x, A5.y, w2, true);
            int w3 = __builtin_amdgcn_cvt_pk_fp8_f32(A6.x, A6.y, 0, false);
            w3 = __builtin_amdgcn_cvt_pk_fp8_f32(A7.x, A7.y, w3, true);
            uint4 w; w.x = (unsigned int)w0; w.y = (unsigned int)w1;
            w.z = (unsigned int)w2; w.w = (unsigned int)w3;
            Als4[(lw >> 4) * 128 + h * 16 + ((lw & 15) ^ h)] = w;
        }
    };

    // ---- prologue: B(0) + chunk 0 fully staged + rowptr/srcs pipeline primed ----
    {
        const ull* Wc = (const ull*)W8;
#pragma unroll
        for (int i = 0; i < 8; ++i) bR[i] = Wc[t + 256 * i];
    }
    int vS3 = rp_load(0);            // val chunk 0 (consumed now)
    int vS2 = rp_load(1);            // val chunk 1
    int vNew = rp_load(2);           // val chunk 2
    int sl0A, sl2A, sl0N, sl2N;
    src_load(vS3, sl0A, sl2A);       // srcs chunk 0
    gat_issue(vS3, sl0A, sl2A);      // gathers chunk 0
    src_load(vS2, sl0A, sl2A);       // srcs chunk 1 (held for loop iter 0)
    agg_consume();                   // Als chunk 0
    vS3 = vS2; vS2 = vNew;
#pragma unroll
    for (int i = 0; i < 8; ++i) {
        int idx = t + 256 * i;
        Bls[gswz8(idx >> 4, idx & 15)] = bR[i];
    }
    __syncthreads();

    // steady state entering iter c: vS3=val[c+1], vS2=val[c+2],
    // (sl0A,sl2A)=srcs[c+1]; Als holds chunk c; Bls[cur] holds chunk c.
    // FULL UNROLL: all guards compile-time, all pipeline state SSA.
#pragma unroll
    for (int c = 0; c < 9; ++c) {
        const int cur = (c & 1) * 2048;
        if (c <= 4) vNew = rp_load(c + 3);               // rowptr chunk c+3
        if (c <= 5) src_load(vS2, sl0N, sl2N);           // srcs chunk c+2
        if (c <= 6) gat_issue(vS3, sl0A, sl2A);          // gathers chunk c+1
        if (c < 8) {                                     // B prefetch chunk c+1
            const ull* Wc = (const ull*)(W8 + (size_t)(c + 1) * 8192);
#pragma unroll
            for (int i = 0; i < 8; ++i) bR[i] = Wc[t + 256 * i];
        }
        if (c == 7) {                                    // root A from x8 rows
#pragma unroll
            for (int i = 0; i < 8; ++i) {
                int rt = i >> 2, kk = i & 3;
                aR[i] = Xr[(size_t)(m0 + wv * 32 + rt * 16 + l15) * 16 + kk * 4 + quad];
            }
        }
#pragma unroll
        for (int kk = 0; kk < 4; ++kk) {
            long long a0, a1;
            if (c == 8) {
                a0 = (long long)aR[kk];
                a1 = (long long)aR[4 + kk];
            } else {
                int j4 = kk * 4 + quad;        // byte-pair group 0..15
                int h2 = j4 >> 1, hf = j4 & 1;
                int slot = ((h2 * 16 + (l15 ^ h2)) << 1) | hf;
                a0 = (long long)AlsW[slot];
                a1 = (long long)AlsW[256 + slot];
            }
            int g = kk * 4 + quad;
#pragma unroll
            for (int nt = 0; nt < 8; ++nt) {
                long long b8 = (long long)Bls[cur + (nt * 16 + l15) * 16 + (g ^ l15)];
                acc[0][nt] = __builtin_amdgcn_mfma_f32_16x16x32_fp8_fp8(a0, b8, acc[0][nt], 0, 0, 0);
                acc[1][nt] = __builtin_amdgcn_mfma_f32_16x16x32_fp8_fp8(a1, b8, acc[1][nt], 0, 0, 0);
            }
        }
        if (c <= 6) agg_consume();             // Als chunk c+1 (wave-private: no barrier)
        if (c < 8) {
            const int nxt = ((c + 1) & 1) * 2048;
#pragma unroll
            for (int i = 0; i < 8; ++i) {
                int idx = t + 256 * i;
                Bls[nxt + gswz8(idx >> 4, idx & 15)] = bR[i];
            }
            __syncthreads();
        }
        vS3 = vS2; vS2 = vNew; sl0A = sl0N; sl2A = sl2N;
    }
#undef ACCUM

    // ---- epilogue: relu, fp8 pack (pi order rows) ----
    ull* outs = (ull*)x8out;
#pragma unroll
    for (int rt = 0; rt < 2; ++rt) {
#pragma unroll
        for (int i = 0; i < 4; ++i) {
            int row = m0 + wv * 32 + rt * 16 + quad * 4 + i;
            float v0 = acc[rt][0][i], v1 = acc[rt][1][i];
            float v2 = acc[rt][2][i], v3 = acc[rt][3][i];
            float v4 = acc[rt][4][i], v5 = acc[rt][5][i];
            float v6 = acc[rt][6][i], v7 = acc[rt][7][i];
            v0 = v0 > 0.f ? v0 : 0.f;  v1 = v1 > 0.f ? v1 : 0.f;
            v2 = v2 > 0.f ? v2 : 0.f;  v3 = v3 > 0.f ? v3 : 0.f;
            v4 = v4 > 0.f ? v4 : 0.f;  v5 = v5 > 0.f ? v5 : 0.f;
            v6 = v6 > 0.f ? v6 : 0.f;  v7 = v7 > 0.f ? v7 : 0.f;
            int lo = __builtin_amdgcn_cvt_pk_fp8_f32(v0, v1, 0, false);
            lo = __builtin_amdgcn_cvt_pk_fp8_f32(v2, v3, lo, true);
            int hi = __builtin_amdgcn_cvt_pk_fp8_f32(v4, v5, 0, false);
            hi = __builtin_amdgcn_cvt_pk_fp8_f32(v6, v7, hi, true);
            if (row < N_NODES) {
                ull w = ((ull)(unsigned int)hi << 32) | (unsigned int)lo;
                outs[(size_t)row * 16 + l15] = w;
            }
        }
    }
}

// ---------------- global mean pool (batch sorted): 64 nodes/wave, fp8 in ----------------
__global__ __launch_bounds__(256) void k_pool(const unsigned int* __restrict__ x8,
                                              const int* __restrict__ batch,
                                              float* __restrict__ gsum) {
    const int wv = threadIdx.x >> 6, lane = threadIdx.x & 63;
    const int n0 = (blockIdx.x * 4 + wv) * 64;
    if (n0 >= N_NODES) return;
    int n1 = n0 + 64;
    if (n1 > N_NODES) n1 = N_NODES;
    const int nb = n1 - n0;
    const unsigned short* xs = (const unsigned short*)x8;   // row = 64 ushorts
    int bb = batch[n0 + (lane < nb ? lane : nb - 1)];
    float2v A = {0.f, 0.f};
    int cur = __shfl(bb, 0);
    for (int base = 0; base < nb; base += 8) {
        unsigned int u[8];
        int m = nb - base;
#pragma unroll
        for (int qq = 0; qq < 8; ++qq)
            if (qq < m) u[qq] = xs[(size_t)(n0 + base + qq) * 64 + lane];
#pragma unroll
        for (int qq = 0; qq < 8; ++qq) {
            if (qq < m) {
                int b = __shfl(bb, base + qq);
                if (b != cur) {
                    atomicAdd(&gsum[cur * 128 + lane * 2], A.x);
                    atomicAdd(&gsum[cur * 128 + lane * 2 + 1], A.y);
                    A = (float2v){0.f, 0.f};
                    cur = b;
                }
                A += __builtin_amdgcn_cvt_pk_f32_fp8((int)u[qq], false);
            }
        }
    }
    atomicAdd(&gsum[cur * 128 + lane * 2], A.x);
    atomicAdd(&gsum[cur * 128 + lane * 2 + 1], A.y);
}

// ---------------- MLP heads (fp32; un-permutes g from pi byte-position order) ----------
__global__ __launch_bounds__(128) void k_heads(
    const float* __restrict__ gsum, const int* __restrict__ gcnt,
    const float* __restrict__ rw1, const float* __restrict__ rb1,
    const float* __restrict__ rw2, const float* __restrict__ rb2,
    const float* __restrict__ sw1, const float* __restrict__ sb1,
    const float* __restrict__ sw2, const float* __restrict__ sb2,
    float* __restrict__ out) {
    __shared__ float g[128];
    __shared__ float parts[2];
    int b = blockIdx.x, t = threadIdx.x;
    int c = gcnt[b];
    float invc = 1.0f / (float)(c > 0 ? c : 1);
    g[((t & 7) << 4) | (t >> 3)] = gsum[b * 128 + t] * invc;   // position -> natural col
    __syncthreads();
    float acc = rb1[t];
    for (int d = 0; d < 128; ++d) acc += g[d] * rw1[d * 128 + t];
    float h = acc > 0.f ? acc : 0.f;
    float p = h * rw2[t];
    for (int o = 32; o > 0; o >>= 1) p += __shfl_down(p, o);
    if ((t & 63) == 0) parts[t >> 6] = p;
    __syncthreads();
    if (t == 0) out[b] = parts[0] + parts[1] + rb2[0];
    __syncthreads();
    acc = sb1[t];
    for (int d = 0; d < 128; ++d) acc += g[d] * sw1[d * 128 + t];
    h = acc > 0.f ? acc : 0.f;
    p = h * sw2[t];
    for (int o = 32; o > 0; o >>= 1) p += __shfl_down(p, o);
    if ((t & 63) == 0) parts[t >> 6] = p;
    __syncthreads();
    if (t == 0) out[64 + b] = parts[0] + parts[1] + sb2[0];
}

extern "C" void kernel_launch(void* const* d_in, const int* in_sizes, int n_in,
                              void* d_out, int out_size, void* d_ws, size_t ws_size,
                              hipStream_t stream) {
    const int*   node_type  = (const int*)d_in[0];
    const int*   edge_index = (const int*)d_in[1];
    const int*   edge_type  = (const int*)d_in[2];
    const int*   batch      = (const int*)d_in[3];
    const float* node_emb   = (const float*)d_in[4];
    const float* rel_w      = (const float*)d_in[5];
    const float* root_w     = (const float*)d_in[6];
    const float* bias       = (const float*)d_in[7];
    const float* rw1        = (const float*)d_in[8];
    const float* rb1        = (const float*)d_in[9];
    const float* rw2        = (const float*)d_in[10];
    const float* rb2        = (const float*)d_in[11];
    const float* sw1        = (const float*)d_in[12];
    const float* sb1        = (const float*)d_in[13];
    const float* sw2        = (const float*)d_in[14];
    const float* sb2        = (const float*)d_in[15];
    float* out = (float*)d_out;

    char* ws = (char*)d_ws;
    size_t off = 0;
    auto alloc = [&](size_t bytes) -> void* {
        void* p = ws + off;
        off += (bytes + 255) & ~(size_t)255;
        return p;
    };
    // ---- persistent region ----
    unsigned int*   x8a    = (unsigned int*)alloc((size_t)N_NODES * 32 * 4);  // 12.8 MB
    unsigned int*   x8b    = (unsigned int*)alloc((size_t)N_NODES * 32 * 4);
    int*            rowptr = (int*)alloc((size_t)(NR + 1) * 4);
    int*            srcs   = (int*)alloc((size_t)N_EDGES * 4);
    int*            bsum   = (int*)alloc(1024 * 4);
    unsigned short* W8     = (unsigned short*)alloc((size_t)W8_TOTAL * 2);
    float*          gsum   = (float*)alloc((64 * 128 + 64) * 4);
    int*            gcnt   = (int*)(gsum + 64 * 128);
    // ---- scratch region: sort temps ----
    int*            cursor = (int*)alloc((size_t)NR * 4);
    int*            counts = (int*)alloc((size_t)NR * 4);
    if (off > ws_size) return;                     // cannot run at all

    // zero scratch via memset nodes (graph-capturable), then fused prep + edge sort
    hipMemsetAsync(counts, 0, (size_t)NR * 4, stream);
    hipMemsetAsync(gsum, 0, (size_t)(64 * 128 + 64) * 4, stream);
    k_prep<<<PB_TOTAL, 256, 0, stream>>>(edge_index, edge_type, counts,
                                         node_type, node_emb, x8a,
                                         rel_w, root_w, W8, batch, gcnt);
    k_scan1<<<NB1, 256, 0, stream>>>(counts, cursor, bsum);
    k_scan2<<<1, 1024, 0, stream>>>(bsum, NB1);
    k_scan3<<<(NR + 255) / 256, 256, 0, stream>>>(cursor, bsum, rowptr, cursor);
    k_scatter<<<(N_EDGES + 255) / 256, 256, 0, stream>>>(edge_index, edge_type, cursor, srcs);

    unsigned int* xcur = x8a;
    unsigned int* xnext = x8b;
    const int gb = (N_NODES + BM2 - 1) / BM2;      // 782
    for (int l = 0; l < N_LAYER; ++l) {
        const unsigned short* W8l = W8 + (size_t)l * 9 * 8192;
        const float* bl = bias + (size_t)l * 128;
        k_gemm<<<gb, 256, 0, stream>>>(xcur, xnext, W8l, bl, rowptr, srcs);
        unsigned int* tmp = xcur; xcur = xnext; xnext = tmp;
    }

    // pool + heads (final activations are in xcur after swap)
    k_pool<<<(N_NODES + 255) / 256, 256, 0, stream>>>(xcur, batch, gsum);
    k_heads<<<64, 128, 0, stream>>>(gsum, gcnt, rw1, rb1, rw2, rb2,
                                    sw1, sb1, sw2, sb2, out);
}